// Round 3
// baseline (720.517 us; speedup 1.0000x reference)
//
#include <hip/hip_runtime.h>
#include <math.h>

// FineGrainLoss: B=96, n1=196 (image tokens), n2=77 (text tokens), d=512.
#define BB 96
#define N1 196
#define N2 77
#define DD 512

#define MT 13   // M tiles of 16 (208 rows, 196 valid)
#define NT 5    // N tiles of 16 (80 cols, 77 valid)
#define NU (MT * NT)   // 65 (strip,ct) units

#define A_CELLS (MT * 64)          // 832 cells (16 B each) per half
#define B_CELLS (NT * 64)          // 320 per half
#define TOT (2 * A_CELLS + 2 * B_CELLS)   // 2304 = 9 * 256

#define IMGN (BB * N1 * DD)
#define TXTN (BB * N2 * DD)

typedef short s8v __attribute__((ext_vector_type(8)));   // 8 bf16 (4 VGPR)
typedef float f4v __attribute__((ext_vector_type(4)));   // MFMA C/D

typedef unsigned int __attribute__((address_space(1))) as1_uint;
typedef unsigned int __attribute__((address_space(3))) as3_uint;

// Async global->LDS, 16 B per lane. LDS dest: wave-uniform base + lane*16.
__device__ __forceinline__ void gload_lds16(const void* g, void* l) {
    __builtin_amdgcn_global_load_lds((const as1_uint*)g, (as3_uint*)l, 16, 0, 0);
}

__device__ __forceinline__ unsigned short f2bf_rn(float x) {
    unsigned int u = __float_as_uint(x);
    unsigned int r = (u + 0x7fffu + ((u >> 16) & 1u)) >> 16;
    return (unsigned short)r;
}
__device__ __forceinline__ float bf2f(unsigned short h) {
    return __uint_as_float(((unsigned int)h) << 16);
}

// fp32 -> (hi, lo) bf16 split, precompute pass.
__global__ void convert_kernel(const float* __restrict__ src,
                               unsigned short* __restrict__ hi,
                               unsigned short* __restrict__ lo, int n) {
    int i = (blockIdx.x * blockDim.x + threadIdx.x) * 4;
    if (i >= n) return;
    float4 v = *(const float4*)(src + i);
    ushort4 h, l;
    h.x = f2bf_rn(v.x); l.x = f2bf_rn(v.x - bf2f(h.x));
    h.y = f2bf_rn(v.y); l.y = f2bf_rn(v.y - bf2f(h.y));
    h.z = f2bf_rn(v.z); l.z = f2bf_rn(v.z - bf2f(h.z));
    h.w = f2bf_rn(v.w); l.w = f2bf_rn(v.w - bf2f(h.w));
    *(ushort4*)(hi + i) = h;
    *(ushort4*)(lo + i) = l;
}

// Per-wave unit range: UB = {0,16,32,48,65} -> counts {16,16,16,17}.
// Units strip-major: u = strip*NT + ct.
template <int U0, int U1>
__device__ __forceinline__ void compute_step(const s8v* __restrict__ frag,
                                             f4v* __restrict__ acc, int fo) {
    s8v bhi[NT], blo[NT];
#pragma unroll
    for (int ct = 0; ct < NT; ++ct) {
        bhi[ct] = frag[2 * A_CELLS + ct * 64 + fo];
        blo[ct] = frag[2 * A_CELLS + B_CELLS + ct * 64 + fo];
    }
    s8v ahi = frag[(U0 / NT) * 64 + fo];
    s8v alo = frag[A_CELLS + (U0 / NT) * 64 + fo];
#pragma unroll
    for (int u = U0; u < U1; ++u) {
        const int s = u / NT, ct = u % NT;
        if (u != U0 && ct == 0) {
            ahi = frag[s * 64 + fo];
            alo = frag[A_CELLS + s * 64 + fo];
        }
        f4v c = acc[u - U0];
        c = __builtin_amdgcn_mfma_f32_16x16x32_bf16(ahi, bhi[ct], c, 0, 0, 0);
        c = __builtin_amdgcn_mfma_f32_16x16x32_bf16(ahi, blo[ct], c, 0, 0, 0);
        c = __builtin_amdgcn_mfma_f32_16x16x32_bf16(alo, bhi[ct], c, 0, 0, 0);
        acc[u - U0] = c;
    }
}

// Per-wave reduction partials. C/D layout: col = lane&15, row = (lane>>4)*4+reg.
// rp: [13 strips][4 waves][16 rows], cp: [80 cols][4 waves].
template <int U0, int U1>
__device__ __forceinline__ void reduce_phase1(const f4v* __restrict__ acc, int wave,
                                              int lq, int lm,
                                              float* __restrict__ rp,
                                              float* __restrict__ cp) {
    constexpr int S0 = U0 / NT;
    constexpr int S1 = (U1 - 1) / NT;
    constexpr int NS = S1 - S0 + 1;
    float colm[NT];
#pragma unroll
    for (int ct = 0; ct < NT; ++ct) colm[ct] = -INFINITY;
    float rowm[NS][4];
#pragma unroll
    for (int i = 0; i < NS; ++i)
#pragma unroll
        for (int r = 0; r < 4; ++r) rowm[i][r] = -INFINITY;

#pragma unroll
    for (int u = U0; u < U1; ++u) {
        const int s = u / NT, ct = u % NT;
        f4v a = acc[u - U0];
        // column partials: mask rows >=196 (strip 12, lq>0)
        bool rows_ok = (s != MT - 1) || (lq == 0);
        float cm = fmaxf(fmaxf(a[0], a[1]), fmaxf(a[2], a[3]));
        colm[ct] = fmaxf(colm[ct], rows_ok ? cm : -INFINITY);
        // row partials: mask cols >=77 (ct 4, lm>=13)
        bool col_ok = (ct != NT - 1) || (lm < N2 - 64);
#pragma unroll
        for (int r = 0; r < 4; ++r)
            rowm[s - S0][r] = fmaxf(rowm[s - S0][r], col_ok ? a[r] : -INFINITY);
    }
#pragma unroll
    for (int ct = 0; ct < NT; ++ct) {
        float m = colm[ct];
        m = fmaxf(m, __shfl_xor(m, 16));
        m = fmaxf(m, __shfl_xor(m, 32));
        if (lq == 0) cp[(ct * 16 + lm) * 4 + wave] = m;
    }
#pragma unroll
    for (int i = 0; i < NS; ++i) {
#pragma unroll
        for (int r = 0; r < 4; ++r) {
            float m = rowm[i][r];
            m = fmaxf(m, __shfl_xor(m, 1));
            m = fmaxf(m, __shfl_xor(m, 2));
            m = fmaxf(m, __shfl_xor(m, 4));
            m = fmaxf(m, __shfl_xor(m, 8));
            if (lm == 0) rp[(S0 + i) * 64 + wave * 16 + lq * 4 + r] = m;
        }
    }
}

// One block per (bi, bt): S[208x80] = img[bi].txt[bt]^T via triple-MFMA bf16
// split, double-buffered global_load_lds staging, one barrier per K-step,
// fused max/mean epilogue. PRE=false falls back to in-kernel fp32 split.
template <bool PRE>
__global__ __launch_bounds__(256, 2) void sim_mfma_kernel(
    const float* __restrict__ imgF, const float* __restrict__ txtF,
    const unsigned short* __restrict__ imgHi, const unsigned short* __restrict__ imgLo,
    const unsigned short* __restrict__ txtHi, const unsigned short* __restrict__ txtLo,
    float* __restrict__ i2t, float* __restrict__ t2i)
{
    const int bt = blockIdx.x, bi = blockIdx.y;
    const int tid = threadIdx.x;
    const int wave = tid >> 6, lane = tid & 63;
    const int lm = lane & 15;
    const int lq = lane >> 4;
    const int fo = lq * 16 + lm;        // frag offset within a 64-cell tile
    const int wv_base = wave * 64;      // wave-uniform LDS staging base (cells)

    __shared__ __align__(16) uint4 cells[2 * TOT];   // 73,728 B (dbuf)
    // reduction scratch aliases the tile (used only after the K loop)
    float* rp  = (float*)cells;          // 832
    float* cp  = (float*)cells + 832;    // 320
    float* sws = (float*)cells + 1152;   // 8

    // ---- staging descriptors (k-invariant) ----
    const unsigned short* gp[9];
    const float* fpp[5];
    int chi[5], clo[5];
    if constexpr (PRE) {
#pragma unroll
        for (int j = 0; j < 9; ++j) {
            int c = tid + 256 * j;  // 2304 cells = 9*256
            if (c < 2 * A_CELLS) {
                int half = (c >= A_CELLS);
                int rem = c - half * A_CELLS;
                int strip = rem >> 6, sub = rem & 63;
                int kb = sub >> 4, m = sub & 15;
                int q = strip * 16 + m; q = q > (N1 - 1) ? (N1 - 1) : q;
                const unsigned short* base = half ? imgLo : imgHi;
                gp[j] = base + ((size_t)(bi * N1 + q) * DD + kb * 8);
            } else {
                int c2 = c - 2 * A_CELLS;
                int half = (c2 >= B_CELLS);
                int rem = c2 - half * B_CELLS;
                int ct = rem >> 6, sub = rem & 63;
                int kb = sub >> 4, n = sub & 15;
                int r = ct * 16 + n; r = r > (N2 - 1) ? (N2 - 1) : r;
                const unsigned short* base = half ? txtLo : txtHi;
                gp[j] = base + ((size_t)(bt * N2 + r) * DD + kb * 8);
            }
        }
    } else {
#pragma unroll
        for (int j = 0; j < 5; ++j) {
            int p = tid + 256 * j;  // 1152 hi/lo cell-pairs
            if (p >= A_CELLS + B_CELLS) { fpp[j] = nullptr; chi[j] = clo[j] = 0; continue; }
            if (p < A_CELLS) {
                int strip = p >> 6, sub = p & 63;
                int kb = sub >> 4, m = sub & 15;
                int q = strip * 16 + m; q = q > (N1 - 1) ? (N1 - 1) : q;
                fpp[j] = imgF + ((size_t)(bi * N1 + q) * DD + kb * 8);
                chi[j] = p; clo[j] = p + A_CELLS;
            } else {
                int p2 = p - A_CELLS;
                int ct = p2 >> 6, sub = p2 & 63;
                int kb = sub >> 4, n = sub & 15;
                int r = ct * 16 + n; r = r > (N2 - 1) ? (N2 - 1) : r;
                fpp[j] = txtF + ((size_t)(bt * N2 + r) * DD + kb * 8);
                chi[j] = 2 * A_CELLS + p2; clo[j] = 2 * A_CELLS + B_CELLS + p2;
            }
        }
    }

    auto stage = [&](int kchunk, int b) {
        const int k0 = kchunk * 32;
        if constexpr (PRE) {
#pragma unroll
            for (int j = 0; j < 9; ++j)
                gload_lds16(gp[j] + k0, &cells[b * TOT + wv_base + 256 * j]);
        } else {
#pragma unroll
            for (int j = 0; j < 5; ++j) {
                if (fpp[j]) {
                    float4 v0 = *(const float4*)(fpp[j] + k0);
                    float4 v1 = *(const float4*)(fpp[j] + k0 + 4);
                    float x[8] = {v0.x, v0.y, v0.z, v0.w, v1.x, v1.y, v1.z, v1.w};
                    unsigned short h[8], l[8];
#pragma unroll
                    for (int e = 0; e < 8; ++e) {
                        h[e] = f2bf_rn(x[e]);
                        l[e] = f2bf_rn(x[e] - bf2f(h[e]));
                    }
                    uint4 hv, lv;
                    hv.x = h[0] | (h[1] << 16); hv.y = h[2] | (h[3] << 16);
                    hv.z = h[4] | (h[5] << 16); hv.w = h[6] | (h[7] << 16);
                    lv.x = l[0] | (l[1] << 16); lv.y = l[2] | (l[3] << 16);
                    lv.z = l[4] | (l[5] << 16); lv.w = l[6] | (l[7] << 16);
                    cells[b * TOT + chi[j]] = hv;
                    cells[b * TOT + clo[j]] = lv;
                }
            }
        }
    };

    f4v acc[17];
#pragma unroll
    for (int i = 0; i < 17; ++i) acc[i] = (f4v){0.f, 0.f, 0.f, 0.f};

    // ---- K loop: dbuf, prefetch-before-compute, ONE barrier per step ----
    stage(0, 0);
    __syncthreads();
#pragma unroll 1
    for (int kc = 0; kc < 16; ++kc) {
        const int cur = kc & 1;
        if (kc + 1 < 16) stage(kc + 1, cur ^ 1);   // async prefetch; drained at barrier
        const s8v* frag = (const s8v*)(cells + cur * TOT);
        if (wave == 0)      compute_step<0, 16>(frag, acc, fo);
        else if (wave == 1) compute_step<16, 32>(frag, acc, fo);
        else if (wave == 2) compute_step<32, 48>(frag, acc, fo);
        else                compute_step<48, 65>(frag, acc, fo);
        __syncthreads();
    }

    // ---- fused reductions (LDS tile re-used as scratch) ----
    for (int i = tid; i < 832; i += 256) rp[i] = -INFINITY;
    __syncthreads();
    if (wave == 0)      reduce_phase1<0, 16>(acc, wave, lq, lm, rp, cp);
    else if (wave == 1) reduce_phase1<16, 32>(acc, wave, lq, lm, rp, cp);
    else if (wave == 2) reduce_phase1<32, 48>(acc, wave, lq, lm, rp, cp);
    else                reduce_phase1<48, 65>(acc, wave, lq, lm, rp, cp);
    __syncthreads();

    float v = 0.f;
    if (tid < N1) {
        int s = tid >> 4, r = tid & 15;
        float m = rp[s * 64 + r];
        m = fmaxf(m, rp[s * 64 + 16 + r]);
        m = fmaxf(m, rp[s * 64 + 32 + r]);
        m = fmaxf(m, rp[s * 64 + 48 + r]);
        v = m;
    }
    v += __shfl_xor(v, 1);  v += __shfl_xor(v, 2);  v += __shfl_xor(v, 4);
    v += __shfl_xor(v, 8);  v += __shfl_xor(v, 16); v += __shfl_xor(v, 32);
    float cv = 0.f;
    if (tid < N2) {
        cv = fmaxf(fmaxf(cp[tid * 4 + 0], cp[tid * 4 + 1]),
                   fmaxf(cp[tid * 4 + 2], cp[tid * 4 + 3]));
    }
    cv += __shfl_xor(cv, 1);  cv += __shfl_xor(cv, 2);  cv += __shfl_xor(cv, 4);
    cv += __shfl_xor(cv, 8);  cv += __shfl_xor(cv, 16); cv += __shfl_xor(cv, 32);
    if (lane == 0) { sws[wave] = v; sws[4 + wave] = cv; }
    __syncthreads();
    if (tid == 0)
        i2t[bi * BB + bt] = (sws[0] + sws[1] + sws[2] + sws[3]) * (1.f / (float)N1);
    if (tid == 1)
        t2i[bt * BB + bi] = (sws[4] + sws[5] + sws[6] + sws[7]) * (1.f / (float)N2);
}

// CE with arange labels over both [B,B] logit matrices.
__global__ __launch_bounds__(256) void ce_kernel(
    const float* __restrict__ i2t, const float* __restrict__ t2i,
    float* __restrict__ out)
{
    const int tid = threadIdx.x;
    const int wid = tid >> 6;
    const int lane = tid & 63;

    float contrib = 0.f;
    if (tid < 2 * BB) {
        const float* M = (tid < BB) ? i2t : t2i;
        const int b = (tid < BB) ? tid : tid - BB;
        const float* row = M + b * BB;
        float mx = row[0];
#pragma unroll 1
        for (int c = 1; c < BB; ++c) mx = fmaxf(mx, row[c]);
        float s = 0.f;
#pragma unroll 1
        for (int c = 0; c < BB; ++c) s += expf(row[c] - mx);
        float lse = mx + logf(s);
        contrib = row[b] - lse;
    }
    contrib += __shfl_xor(contrib, 1);
    contrib += __shfl_xor(contrib, 2);
    contrib += __shfl_xor(contrib, 4);
    contrib += __shfl_xor(contrib, 8);
    contrib += __shfl_xor(contrib, 16);
    contrib += __shfl_xor(contrib, 32);

    __shared__ float s_part[4];
    if (lane == 0) s_part[wid] = contrib;
    __syncthreads();
    if (tid == 0) {
        float total = s_part[0] + s_part[1] + s_part[2] + s_part[3];
        out[0] = -total * (1.f / (float)(2 * BB));
    }
}

extern "C" void kernel_launch(void* const* d_in, const int* in_sizes, int n_in,
                              void* d_out, int out_size, void* d_ws, size_t ws_size,
                              hipStream_t stream) {
    const float* img = (const float*)d_in[0];   // [96,196,512] fp32
    const float* txt = (const float*)d_in[1];   // [96,77,512] fp32
    float* i2t = (float*)d_ws;                  // [96,96]
    float* t2i = i2t + BB * BB;                 // [96,96]

    const size_t conv_off = 2 * BB * BB * sizeof(float);
    const size_t need = conv_off + (size_t)(IMGN + TXTN) * 2 * sizeof(unsigned short);

    dim3 grid(BB, BB);
    if (ws_size >= need) {
        unsigned short* imgHi = (unsigned short*)((char*)d_ws + conv_off);
        unsigned short* imgLo = imgHi + IMGN;
        unsigned short* txtHi = imgLo + IMGN;
        unsigned short* txtLo = txtHi + TXTN;
        convert_kernel<<<(IMGN / 4 + 255) / 256, 256, 0, stream>>>(img, imgHi, imgLo, IMGN);
        convert_kernel<<<(TXTN / 4 + 255) / 256, 256, 0, stream>>>(txt, txtHi, txtLo, TXTN);
        sim_mfma_kernel<true><<<grid, 256, 0, stream>>>(
            img, txt, imgHi, imgLo, txtHi, txtLo, i2t, t2i);
    } else {
        sim_mfma_kernel<false><<<grid, 256, 0, stream>>>(
            img, txt, nullptr, nullptr, nullptr, nullptr, i2t, t2i);
    }
    ce_kernel<<<1, 256, 0, stream>>>(i2t, t2i, (float*)d_out);
}